// Round 5
// baseline (348.820 us; speedup 1.0000x reference)
//
#include <hip/hip_runtime.h>
#include <hip/hip_fp16.h>

// SSN soft-superpixel assignment. Fixed shapes: x (4,32,256,256) fp32, s=16.
// M = 0 -> grid channels are identically zero; drop them (C=32).
//
// ROUND 5: replace hipMemsetAsync with OUR OWN fill-style zero kernel.
// Ledger so far: in-kernel interleaved zero stores -> ~315 us total (all
// structures, NT or plain); no in-kernel stores + graph memset node -> 342 us.
// The harness's own fillBufferAligned zeroes a 1 GiB region at 6.1 TB/s, so a
// pure streaming store kernel CAN write this memory fast. k_zero is built to
// be structurally identical to that fill: grid-stride dwordx4 stores, no LDS,
// no barriers, minimal registers. This either (a) drops the zeroing cost to
// ~45 us (win), or (b) surfaces k_zero in the rocprof top-5 at ~1 TB/s,
// proving the write path itself is capped for compute-queue kernels.
#define B_  4
#define C_  32
#define W_  256
#define N_  65536   // H*W
#define NH_ 16      // 16x16 superpixel grid
#define S_  256
#define PADP 260    // xsh row stride (floats): 1040 B = 16B-mult, 4-way b128 conflict only
#define PADH 260    // affs row stride (halves): 520 B, 8B-mult for half4 reads
#define PSTR 304    // per-block partial stride: 288 num + 9 den + pad

typedef float vf4 __attribute__((ext_vector_type(4)));
typedef _Float16 h4 __attribute__((ext_vector_type(4)));

__device__ __forceinline__ float wave_sum(float v) {
    v += __shfl_down(v, 32);
    v += __shfl_down(v, 16);
    v += __shfl_down(v, 8);
    v += __shfl_down(v, 4);
    v += __shfl_down(v, 2);
    v += __shfl_down(v, 1);
    return v;  // lane 0 holds the 64-lane sum
}

__device__ __forceinline__ void st4(float* p, float a, float b, float c, float d) {
    vf4 v = {a, b, c, d};
    *(vf4*)p = v;
}

// Fill-style streaming zero of the whole output tensor (67,108,864 floats =
// 16,777,216 float4s). 2048 blocks x 256 threads; each thread stores 32
// dwordx4, wave-contiguous 1 KB segments, 8 MB stride between iterations.
// No LDS, no barriers — structurally identical to __amd_rocclr_fillBufferAligned.
__global__ __launch_bounds__(256) void k_zero(float* __restrict__ out) {
    const size_t tid = (size_t)blockIdx.x * 256 + threadIdx.x;   // 0 .. 524287
    vf4* p = (vf4*)out;
    const vf4 z = {0.f, 0.f, 0.f, 0.f};
    #pragma unroll 4
    for (int i = 0; i < 32; ++i)
        p[tid + (size_t)i * 524288] = z;
}

// Stage this block's 16x16x32 tile of x into xsh[c][p] (p = py*16+px),
// coalesced float4: idx -> channel c = idx>>6, f4 p4 = idx&63.
__device__ __forceinline__ void stage_tile(const float* __restrict__ x,
                                           int b, int sy, int sx, int t,
                                           float (*xsh)[PADP]) {
    const float* base = x + (size_t)b * C_ * N_ + (sy * 16) * W_ + sx * 16;
    #pragma unroll
    for (int i = 0; i < 8; ++i) {
        const int idx = i * 256 + t;
        const int c = idx >> 6, p4 = idx & 63;
        const float4 v = *(const float4*)(base + (size_t)c * N_ + (p4 >> 2) * W_ + (p4 & 3) * 4);
        *(float4*)&xsh[c][p4 * 4] = v;
    }
}

// Per-pixel softmax over the 3x3 superpixel neighborhood (cl[k] zeroed for
// invalid k; masked to aff=0 anyway). Equivalent to ref softmax(-dist)+mask.
__device__ __forceinline__ void compute_aff(const float xv[C_], const float (*cl)[C_],
                                            int sy, int sx, float aff[9]) {
    float dist[9];
    #pragma unroll
    for (int k = 0; k < 9; ++k) {
        const int ny = sy + k / 3 - 1, nx = sx + k % 3 - 1;
        const bool valid = (ny >= 0) & (ny < NH_) & (nx >= 0) & (nx < NH_);
        float d = 0.f;
        #pragma unroll
        for (int c4 = 0; c4 < C_ / 4; ++c4) {
            const float4 cv = *(const float4*)&cl[k][c4 * 4];   // LDS broadcast
            const float d0 = xv[c4 * 4 + 0] - cv.x;
            const float d1 = xv[c4 * 4 + 1] - cv.y;
            const float d2 = xv[c4 * 4 + 2] - cv.z;
            const float d3 = xv[c4 * 4 + 3] - cv.w;
            d += d0 * d0 + d1 * d1 + d2 * d2 + d3 * d3;
        }
        dist[k] = valid ? d : 1e30f;
    }
    float mind = dist[0];
    #pragma unroll
    for (int k = 1; k < 9; ++k) mind = fminf(mind, dist[k]);
    float sum = 0.f;
    #pragma unroll
    for (int k = 0; k < 9; ++k) {
        const float e = (dist[k] < 1e29f) ? __expf(mind - dist[k]) : 0.f;
        aff[k] = e;
        sum += e;
    }
    const float inv = 1.f / sum;   // home superpixel always valid
    #pragma unroll
    for (int k = 0; k < 9; ++k) aff[k] *= inv;
}

// cent1[b,(ny,nx),c] = num/(den+1e-16), gathered from 9 source blocks'
// partials (part is L2-hot, 1.2 MB).
__device__ __forceinline__ float gather_cent1(const float* __restrict__ part,
                                              int b, int ny, int nx, int c) {
    float num = 0.f, den = 0.f;
    #pragma unroll
    for (int k2 = 0; k2 < 9; ++k2) {
        const int syp = ny - (k2 / 3 - 1), sxp = nx - (k2 % 3 - 1);
        if ((syp >= 0) & (syp < NH_) & (sxp >= 0) & (sxp < NH_)) {
            const size_t base = (size_t)(b * S_ + syp * NH_ + sxp) * PSTR;
            num += part[base + k2 * 32 + c];
            den += part[base + 288 + k2];
        }
    }
    return num / (den + 1e-16f);
}

// K1: initial centroids = tile means.
__global__ __launch_bounds__(256) void k_cent0(const float* __restrict__ x,
                                               float* __restrict__ cent0) {
    const int blk = blockIdx.x;            // b*S_ + s
    const int b = blk >> 8, s = blk & 255;
    const int sy = s >> 4, sx = s & 15;
    const int t = threadIdx.x;
    const int w = t >> 6, lane = t & 63;
    const float* base = x + (size_t)b * C_ * N_ + (sy * 16) * W_ + sx * 16;
    #pragma unroll
    for (int i = 0; i < 8; ++i) {
        const int c = i * 4 + w;
        const float4 v = *(const float4*)(base + (size_t)c * N_ + (lane >> 2) * W_ + (lane & 3) * 4);
        const float sm = wave_sum(v.x + v.y + v.z + v.w);
        if (lane == 0) cent0[(size_t)blk * C_ + c] = sm * (1.0f / 256.0f);
    }
}

// K2: iteration-0 affinities + num/den partials (no output zeroing).
__global__ __launch_bounds__(256, 4) void k_part(const float* __restrict__ x,
                                                 const float* __restrict__ cent0,
                                                 float* __restrict__ part) {
    const int blk = blockIdx.x;
    const int b = blk >> 8, s = blk & 255;
    const int sy = s >> 4, sx = s & 15;
    const int t = threadIdx.x;
    const int w = t >> 6, lane = t & 63;
    __shared__ float cl[9][C_];
    __shared__ float xsh[C_][PADP];
    __shared__ _Float16 affs[9][PADH];
    __shared__ float lden[4][9];
    {   // cl fill: k=0..7 by all, k=8 by t<32
        const int k = t >> 5, c = t & 31;
        const int ny = sy + k / 3 - 1, nx = sx + k % 3 - 1;
        const bool valid = (ny >= 0) & (ny < NH_) & (nx >= 0) & (nx < NH_);
        cl[k][c] = valid ? cent0[(size_t)(b * S_ + ny * NH_ + nx) * C_ + c] : 0.f;
    }
    if (t < 32) {
        const int ny = sy + 1, nx = sx + 1;
        const bool valid = (ny < NH_) & (nx < NH_);
        cl[8][t] = valid ? cent0[(size_t)(b * S_ + ny * NH_ + nx) * C_ + t] : 0.f;
    }
    stage_tile(x, b, sy, sx, t, xsh);
    __syncthreads();
    float xv[C_];
    #pragma unroll
    for (int c = 0; c < C_; ++c) xv[c] = xsh[c][t];   // conflict-free
    float aff[9];
    compute_aff(xv, cl, sy, sx, aff);
    #pragma unroll
    for (int k = 0; k < 9; ++k) {
        affs[k][t] = (_Float16)aff[k];
        const float v = wave_sum(aff[k]);
        if (lane == 0) lden[w][k] = v;
    }
    __syncthreads();
    {   // Phase B: outputs t = k*32+c for k=0..7; t<32 also k=8.
        const int k = t >> 5, c = t & 31;
        float acc = 0.f;
        #pragma unroll 4
        for (int p = 0; p < 256; p += 4) {
            const h4 a = *(const h4*)&affs[k][p];
            const float4 xc = *(const float4*)&xsh[c][p];
            acc += (float)a.x * xc.x + (float)a.y * xc.y +
                   (float)a.z * xc.z + (float)a.w * xc.w;
        }
        part[(size_t)blk * PSTR + t] = acc;
    }
    if (t < 32) {
        float acc = 0.f;
        #pragma unroll 4
        for (int p = 0; p < 256; p += 4) {
            const h4 a = *(const h4*)&affs[8][p];
            const float4 xc = *(const float4*)&xsh[t][p];
            acc += (float)a.x * xc.x + (float)a.y * xc.y +
                   (float)a.z * xc.z + (float)a.w * xc.w;
        }
        part[(size_t)blk * PSTR + 256 + t] = acc;
    }
    if (t < 9)
        part[(size_t)blk * PSTR + 288 + t] =
            lden[0][t] + lden[1][t] + lden[2][t] + lden[3][t];
}

// K3: iteration-1 affinities vs cent1 (gathered in-kernel) + direct value
// scatter from LDS into the pre-zeroed output planes.
__global__ __launch_bounds__(256, 4) void k_aff9(const float* __restrict__ x,
                                                 const float* __restrict__ part,
                                                 float* __restrict__ out) {
    const int blk = blockIdx.x;
    const int b = blk >> 8, s = blk & 255;
    const int sy = s >> 4, sx = s & 15;
    const int t = threadIdx.x;
    __shared__ float cl[9][C_];
    __shared__ float xsh[C_][PADP];
    __shared__ _Float16 affs[9][PADH];
    {   // cl = cent1 of the 9 neighbors, computed on the fly
        const int k = t >> 5, c = t & 31;
        const int ny = sy + k / 3 - 1, nx = sx + k % 3 - 1;
        const bool valid = (ny >= 0) & (ny < NH_) & (nx >= 0) & (nx < NH_);
        cl[k][c] = valid ? gather_cent1(part, b, ny, nx, c) : 0.f;
    }
    if (t < 32) {
        const int ny = sy + 1, nx = sx + 1;
        const bool valid = (ny < NH_) & (nx < NH_);
        cl[8][t] = valid ? gather_cent1(part, b, ny, nx, t) : 0.f;
    }
    stage_tile(x, b, sy, sx, t, xsh);
    __syncthreads();
    float xv[C_];
    #pragma unroll
    for (int c = 0; c < C_; ++c) xv[c] = xsh[c][t];
    float aff[9];
    compute_aff(xv, cl, sy, sx, aff);
    #pragma unroll
    for (int k = 0; k < 9; ++k) affs[k][t] = (_Float16)aff[k];
    __syncthreads();
    // Scatter: for valid neighbor k, write this tile's 16x16 values into
    // plane s'=(ny,nx) — 576 float4 total (64B row-segments).
    #pragma unroll
    for (int i = 0; i < 3; ++i) {
        const int idx = i * 256 + t;
        if (idx < 576) {
            const int k = idx >> 6, j4 = idx & 63;
            const int ny = sy + k / 3 - 1, nx = sx + k % 3 - 1;
            if ((ny >= 0) & (ny < NH_) & (nx >= 0) & (nx < NH_)) {
                const h4 a = *(const h4*)&affs[k][j4 * 4];
                const int gq = (sy * 16 + (j4 >> 2)) * 64 + sx * 4 + (j4 & 3);
                float* dst = out + (((size_t)(b * S_ + ny * NH_ + nx) << 16) + gq * 4);
                st4(dst, (float)a.x, (float)a.y, (float)a.z, (float)a.w);
            }
        }
    }
    if ((blk | t) == 0) out[(size_t)B_ * S_ * N_] = 256.0f;  // output 1: S
}

extern "C" void kernel_launch(void* const* d_in, const int* in_sizes, int n_in,
                              void* d_out, int out_size, void* d_ws, size_t ws_size,
                              hipStream_t stream) {
    const float* x = (const float*)d_in[0];
    float* ws = (float*)d_ws;
    // ws layout (floats): cent0[32768] | part[1024*304]
    float* cent0 = ws;
    float* part  = ws + 32768;
    float* out   = (float*)d_out;

    // Zero the output with our own fill-style streaming kernel (see header
    // comment). Stream-ordered: zeros land before k_aff9's value scatter.
    hipLaunchKernelGGL(k_zero,  dim3(2048),    dim3(256), 0, stream, out);
    hipLaunchKernelGGL(k_cent0, dim3(B_ * S_), dim3(256), 0, stream, x, cent0);
    hipLaunchKernelGGL(k_part,  dim3(B_ * S_), dim3(256), 0, stream, x, cent0, part);
    hipLaunchKernelGGL(k_aff9,  dim3(B_ * S_), dim3(256), 0, stream, x, part, out);
}

// Round 6
// 348.677 us; speedup vs baseline: 1.0004x; 1.0004x over previous
//
#include <hip/hip_runtime.h>
#include <hip/hip_fp16.h>
#include <hip/hip_cooperative_groups.h>

namespace cg = cooperative_groups;

// SSN soft-superpixel assignment. Fixed shapes: x (4,32,256,256) fp32, s=16.
// M = 0 -> grid channels are identically zero; drop them (C=32).
//
// ROUND 6: single cooperative kernel (R2 structure, measured 317.9 us at
// 0.9 TB/s effective write BW with ALL pipes idle), changing ONE variable:
// the zero-store address mapping. R2 had each block zero its own 256 KB
// output plane -> 1024 concurrent store streams at exactly 256 KB stride,
// lockstep on the same HBM-channel subset. Now blocks zero the output
// LINEARLY (sweep i: block b, thread t -> float4 index (i*1024+b)*256+t),
// the same address shape as the 6 TB/s fill kernels. Scatter targets are
// zeroed too (no EXCL mask); phase-2's value scatter overwrites them after
// the second grid.sync, so ordering is structural.
#define B_  4
#define C_  32
#define W_  256
#define N_  65536   // H*W
#define NH_ 16      // 16x16 superpixel grid
#define S_  256
#define PADP 260    // xsh row stride (floats): 1040 B = 16B-mult, 4-way b128 conflict only
#define PADH 260    // affs row stride (halves): 520 B, 8B-mult for half4 reads
#define PSTR 304    // per-block partial stride: 288 num + 9 den + pad

typedef float vf4 __attribute__((ext_vector_type(4)));
typedef _Float16 h4 __attribute__((ext_vector_type(4)));

__device__ __forceinline__ float wave_sum(float v) {
    v += __shfl_down(v, 32);
    v += __shfl_down(v, 16);
    v += __shfl_down(v, 8);
    v += __shfl_down(v, 4);
    v += __shfl_down(v, 2);
    v += __shfl_down(v, 1);
    return v;  // lane 0 holds the 64-lane sum
}

__device__ __forceinline__ void st4(float* p, float a, float b, float c, float d) {
    vf4 v = {a, b, c, d};
    *(vf4*)p = v;
}

// Linear zero sweeps [i0,i1): whole-grid-contiguous 4 MB per sweep,
// consecutive blocks adjacent, same address shape as fillBufferAligned.
// 64 sweeps cover all 16,777,216 float4s of out.
__device__ __forceinline__ void zero_linear(float* out, int blk, int t,
                                            int i0, int i1) {
    vf4* p = (vf4*)out;
    const size_t base = (size_t)blk * 256 + t;
    const vf4 z = {0.f, 0.f, 0.f, 0.f};
    #pragma unroll 8
    for (int i = i0; i < i1; ++i)
        p[base + (size_t)i * 262144] = z;
}

// Stage this block's 16x16x32 tile of x into xsh[c][p] (p = py*16+px),
// coalesced float4: idx -> channel c = idx>>6, f4 p4 = idx&63.
__device__ __forceinline__ void stage_tile(const float* __restrict__ x,
                                           int b, int sy, int sx, int t,
                                           float (*xsh)[PADP]) {
    const float* base = x + (size_t)b * C_ * N_ + (sy * 16) * W_ + sx * 16;
    #pragma unroll
    for (int i = 0; i < 8; ++i) {
        const int idx = i * 256 + t;
        const int c = idx >> 6, p4 = idx & 63;
        const float4 v = *(const float4*)(base + (size_t)c * N_ + (p4 >> 2) * W_ + (p4 & 3) * 4);
        *(float4*)&xsh[c][p4 * 4] = v;
    }
}

// Per-pixel softmax over the 3x3 superpixel neighborhood (cl[k] zeroed for
// invalid k; masked to aff=0 anyway). Equivalent to ref softmax(-dist)+mask.
__device__ __forceinline__ void compute_aff(const float xv[C_], const float (*cl)[C_],
                                            int sy, int sx, float aff[9]) {
    float dist[9];
    #pragma unroll
    for (int k = 0; k < 9; ++k) {
        const int ny = sy + k / 3 - 1, nx = sx + k % 3 - 1;
        const bool valid = (ny >= 0) & (ny < NH_) & (nx >= 0) & (nx < NH_);
        float d = 0.f;
        #pragma unroll
        for (int c4 = 0; c4 < C_ / 4; ++c4) {
            const float4 cv = *(const float4*)&cl[k][c4 * 4];   // LDS broadcast
            const float d0 = xv[c4 * 4 + 0] - cv.x;
            const float d1 = xv[c4 * 4 + 1] - cv.y;
            const float d2 = xv[c4 * 4 + 2] - cv.z;
            const float d3 = xv[c4 * 4 + 3] - cv.w;
            d += d0 * d0 + d1 * d1 + d2 * d2 + d3 * d3;
        }
        dist[k] = valid ? d : 1e30f;
    }
    float mind = dist[0];
    #pragma unroll
    for (int k = 1; k < 9; ++k) mind = fminf(mind, dist[k]);
    float sum = 0.f;
    #pragma unroll
    for (int k = 0; k < 9; ++k) {
        const float e = (dist[k] < 1e29f) ? __expf(mind - dist[k]) : 0.f;
        aff[k] = e;
        sum += e;
    }
    const float inv = 1.f / sum;   // home superpixel always valid
    #pragma unroll
    for (int k = 0; k < 9; ++k) aff[k] *= inv;
}

// cent1[b,(ny,nx),c] = num/(den+1e-16), gathered from 9 source blocks'
// partials (part is L2-hot, 1.2 MB).
__device__ __forceinline__ float gather_cent1(const float* __restrict__ part,
                                              int b, int ny, int nx, int c) {
    float num = 0.f, den = 0.f;
    #pragma unroll
    for (int k2 = 0; k2 < 9; ++k2) {
        const int syp = ny - (k2 / 3 - 1), sxp = nx - (k2 % 3 - 1);
        if ((syp >= 0) & (syp < NH_) & (sxp >= 0) & (sxp < NH_)) {
            const size_t base = (size_t)(b * S_ + syp * NH_ + sxp) * PSTR;
            num += part[base + k2 * 32 + c];
            den += part[base + 288 + k2];
        }
    }
    return num / (den + 1e-16f);
}

// ---------------------------------------------------------------------------
// Fused cooperative kernel
// ---------------------------------------------------------------------------
__global__ __launch_bounds__(256, 4) void k_fused(const float* __restrict__ x,
                                                  float* __restrict__ cent0,
                                                  float* __restrict__ part,
                                                  float* __restrict__ out) {
    const int blk = blockIdx.x;            // b*S_ + s
    const int b = blk >> 8, s = blk & 255;
    const int sy = s >> 4, sx = s & 15;
    const int t = threadIdx.x;
    const int w = t >> 6, lane = t & 63;
    __shared__ float cl[9][C_];
    __shared__ float xsh[C_][PADP];
    __shared__ _Float16 affs[9][PADH];
    __shared__ float lden[4][9];

    // ---- Phase 0: stage x once; zero sweeps [0,32); cent0 from LDS ----
    stage_tile(x, b, sy, sx, t, xsh);
    zero_linear(out, blk, t, 0, 32);
    __syncthreads();
    #pragma unroll
    for (int i = 0; i < 8; ++i) {
        const int c = i * 4 + w;           // wave w covers channels {w,4+w,...}
        const float4 v = *(const float4*)&xsh[c][lane * 4];  // contiguous 1 KB/wave
        const float sm = wave_sum(v.x + v.y + v.z + v.w);
        if (lane == 0) cent0[(size_t)blk * C_ + c] = sm * (1.0f / 256.0f);
    }
    cg::this_grid().sync();

    // ---- Phase 1: iteration-0 affinities + partials; zero sweeps [32,64) ----
    {   // cl fill: k=0..7 by all, k=8 by t<32
        const int k = t >> 5, c = t & 31;
        const int ny = sy + k / 3 - 1, nx = sx + k % 3 - 1;
        const bool valid = (ny >= 0) & (ny < NH_) & (nx >= 0) & (nx < NH_);
        cl[k][c] = valid ? cent0[(size_t)(b * S_ + ny * NH_ + nx) * C_ + c] : 0.f;
    }
    if (t < 32) {
        const int ny = sy + 1, nx = sx + 1;
        const bool valid = (ny < NH_) & (nx < NH_);
        cl[8][t] = valid ? cent0[(size_t)(b * S_ + ny * NH_ + nx) * C_ + t] : 0.f;
    }
    zero_linear(out, blk, t, 32, 64);
    __syncthreads();
    float xv[C_];
    #pragma unroll
    for (int c = 0; c < C_; ++c) xv[c] = xsh[c][t];   // conflict-free
    float aff[9];
    compute_aff(xv, cl, sy, sx, aff);
    #pragma unroll
    for (int k = 0; k < 9; ++k) {
        affs[k][t] = (_Float16)aff[k];
        const float v = wave_sum(aff[k]);
        if (lane == 0) lden[w][k] = v;
    }
    __syncthreads();
    {   // Phase B: outputs t = k*32+c for k=0..7; t<32 also k=8.
        const int k = t >> 5, c = t & 31;
        float acc = 0.f;
        #pragma unroll 4
        for (int p = 0; p < 256; p += 4) {
            const h4 a = *(const h4*)&affs[k][p];
            const float4 xc = *(const float4*)&xsh[c][p];
            acc += (float)a.x * xc.x + (float)a.y * xc.y +
                   (float)a.z * xc.z + (float)a.w * xc.w;
        }
        part[(size_t)blk * PSTR + t] = acc;
    }
    if (t < 32) {
        float acc = 0.f;
        #pragma unroll 4
        for (int p = 0; p < 256; p += 4) {
            const h4 a = *(const h4*)&affs[8][p];
            const float4 xc = *(const float4*)&xsh[t][p];
            acc += (float)a.x * xc.x + (float)a.y * xc.y +
                   (float)a.z * xc.z + (float)a.w * xc.w;
        }
        part[(size_t)blk * PSTR + 256 + t] = acc;
    }
    if (t < 9)
        part[(size_t)blk * PSTR + 288 + t] =
            lden[0][t] + lden[1][t] + lden[2][t] + lden[3][t];
    cg::this_grid().sync();           // zeros + partials visible grid-wide

    // ---- Phase 2: iteration-1 affinities vs gathered cent1 + value scatter
    //      (overwrites the pre-zeroed scatter targets) ----
    {   // cl = cent1 of the 9 neighbors, computed on the fly
        const int k = t >> 5, c = t & 31;
        const int ny = sy + k / 3 - 1, nx = sx + k % 3 - 1;
        const bool valid = (ny >= 0) & (ny < NH_) & (nx >= 0) & (nx < NH_);
        cl[k][c] = valid ? gather_cent1(part, b, ny, nx, c) : 0.f;
    }
    if (t < 32) {
        const int ny = sy + 1, nx = sx + 1;
        const bool valid = (ny < NH_) & (nx < NH_);
        cl[8][t] = valid ? gather_cent1(part, b, ny, nx, t) : 0.f;
    }
    __syncthreads();
    #pragma unroll
    for (int c = 0; c < C_; ++c) xv[c] = xsh[c][t];
    compute_aff(xv, cl, sy, sx, aff);
    #pragma unroll
    for (int k = 0; k < 9; ++k) affs[k][t] = (_Float16)aff[k];
    __syncthreads();
    // Scatter: for valid neighbor k, write this tile's 16x16 values into
    // plane s'=(ny,nx) — 576 float4 total (64B row-segments).
    #pragma unroll
    for (int i = 0; i < 3; ++i) {
        const int idx = i * 256 + t;
        if (idx < 576) {
            const int k = idx >> 6, j4 = idx & 63;
            const int ny = sy + k / 3 - 1, nx = sx + k % 3 - 1;
            if ((ny >= 0) & (ny < NH_) & (nx >= 0) & (nx < NH_)) {
                const h4 a = *(const h4*)&affs[k][j4 * 4];
                const int gq = (sy * 16 + (j4 >> 2)) * 64 + sx * 4 + (j4 & 3);
                float* dst = out + (((size_t)(b * S_ + ny * NH_ + nx) << 16) + gq * 4);
                st4(dst, (float)a.x, (float)a.y, (float)a.z, (float)a.w);
            }
        }
    }
    if ((blk | t) == 0) out[(size_t)B_ * S_ * N_] = 256.0f;  // output 1: S
}

// ---------------------------------------------------------------------------
// 4-kernel fallback (R5 structure, verified) if coop launch is rejected
// ---------------------------------------------------------------------------
__global__ __launch_bounds__(256) void k_zero(float* __restrict__ out) {
    const size_t tid = (size_t)blockIdx.x * 256 + threadIdx.x;   // 0 .. 524287
    vf4* p = (vf4*)out;
    const vf4 z = {0.f, 0.f, 0.f, 0.f};
    #pragma unroll 4
    for (int i = 0; i < 32; ++i)
        p[tid + (size_t)i * 524288] = z;
}

__global__ __launch_bounds__(256) void k_cent0(const float* __restrict__ x,
                                               float* __restrict__ cent0) {
    const int blk = blockIdx.x;            // b*S_ + s
    const int b = blk >> 8, s = blk & 255;
    const int sy = s >> 4, sx = s & 15;
    const int t = threadIdx.x;
    const int w = t >> 6, lane = t & 63;
    const float* base = x + (size_t)b * C_ * N_ + (sy * 16) * W_ + sx * 16;
    #pragma unroll
    for (int i = 0; i < 8; ++i) {
        const int c = i * 4 + w;
        const float4 v = *(const float4*)(base + (size_t)c * N_ + (lane >> 2) * W_ + (lane & 3) * 4);
        const float sm = wave_sum(v.x + v.y + v.z + v.w);
        if (lane == 0) cent0[(size_t)blk * C_ + c] = sm * (1.0f / 256.0f);
    }
}

__global__ __launch_bounds__(256, 4) void k_part(const float* __restrict__ x,
                                                 const float* __restrict__ cent0,
                                                 float* __restrict__ part) {
    const int blk = blockIdx.x;
    const int b = blk >> 8, s = blk & 255;
    const int sy = s >> 4, sx = s & 15;
    const int t = threadIdx.x;
    const int w = t >> 6, lane = t & 63;
    __shared__ float cl[9][C_];
    __shared__ float xsh[C_][PADP];
    __shared__ _Float16 affs[9][PADH];
    __shared__ float lden[4][9];
    {
        const int k = t >> 5, c = t & 31;
        const int ny = sy + k / 3 - 1, nx = sx + k % 3 - 1;
        const bool valid = (ny >= 0) & (ny < NH_) & (nx >= 0) & (nx < NH_);
        cl[k][c] = valid ? cent0[(size_t)(b * S_ + ny * NH_ + nx) * C_ + c] : 0.f;
    }
    if (t < 32) {
        const int ny = sy + 1, nx = sx + 1;
        const bool valid = (ny < NH_) & (nx < NH_);
        cl[8][t] = valid ? cent0[(size_t)(b * S_ + ny * NH_ + nx) * C_ + t] : 0.f;
    }
    stage_tile(x, b, sy, sx, t, xsh);
    __syncthreads();
    float xv[C_];
    #pragma unroll
    for (int c = 0; c < C_; ++c) xv[c] = xsh[c][t];
    float aff[9];
    compute_aff(xv, cl, sy, sx, aff);
    #pragma unroll
    for (int k = 0; k < 9; ++k) {
        affs[k][t] = (_Float16)aff[k];
        const float v = wave_sum(aff[k]);
        if (lane == 0) lden[w][k] = v;
    }
    __syncthreads();
    {
        const int k = t >> 5, c = t & 31;
        float acc = 0.f;
        #pragma unroll 4
        for (int p = 0; p < 256; p += 4) {
            const h4 a = *(const h4*)&affs[k][p];
            const float4 xc = *(const float4*)&xsh[c][p];
            acc += (float)a.x * xc.x + (float)a.y * xc.y +
                   (float)a.z * xc.z + (float)a.w * xc.w;
        }
        part[(size_t)blk * PSTR + t] = acc;
    }
    if (t < 32) {
        float acc = 0.f;
        #pragma unroll 4
        for (int p = 0; p < 256; p += 4) {
            const h4 a = *(const h4*)&affs[8][p];
            const float4 xc = *(const float4*)&xsh[t][p];
            acc += (float)a.x * xc.x + (float)a.y * xc.y +
                   (float)a.z * xc.z + (float)a.w * xc.w;
        }
        part[(size_t)blk * PSTR + 256 + t] = acc;
    }
    if (t < 9)
        part[(size_t)blk * PSTR + 288 + t] =
            lden[0][t] + lden[1][t] + lden[2][t] + lden[3][t];
}

__global__ __launch_bounds__(256, 4) void k_aff9(const float* __restrict__ x,
                                                 const float* __restrict__ part,
                                                 float* __restrict__ out) {
    const int blk = blockIdx.x;
    const int b = blk >> 8, s = blk & 255;
    const int sy = s >> 4, sx = s & 15;
    const int t = threadIdx.x;
    __shared__ float cl[9][C_];
    __shared__ float xsh[C_][PADP];
    __shared__ _Float16 affs[9][PADH];
    {
        const int k = t >> 5, c = t & 31;
        const int ny = sy + k / 3 - 1, nx = sx + k % 3 - 1;
        const bool valid = (ny >= 0) & (ny < NH_) & (nx >= 0) & (nx < NH_);
        cl[k][c] = valid ? gather_cent1(part, b, ny, nx, c) : 0.f;
    }
    if (t < 32) {
        const int ny = sy + 1, nx = sx + 1;
        const bool valid = (ny < NH_) & (nx < NH_);
        cl[8][t] = valid ? gather_cent1(part, b, ny, nx, t) : 0.f;
    }
    stage_tile(x, b, sy, sx, t, xsh);
    __syncthreads();
    float xv[C_];
    #pragma unroll
    for (int c = 0; c < C_; ++c) xv[c] = xsh[c][t];
    float aff[9];
    compute_aff(xv, cl, sy, sx, aff);
    #pragma unroll
    for (int k = 0; k < 9; ++k) affs[k][t] = (_Float16)aff[k];
    __syncthreads();
    #pragma unroll
    for (int i = 0; i < 3; ++i) {
        const int idx = i * 256 + t;
        if (idx < 576) {
            const int k = idx >> 6, j4 = idx & 63;
            const int ny = sy + k / 3 - 1, nx = sx + k % 3 - 1;
            if ((ny >= 0) & (ny < NH_) & (nx >= 0) & (nx < NH_)) {
                const h4 a = *(const h4*)&affs[k][j4 * 4];
                const int gq = (sy * 16 + (j4 >> 2)) * 64 + sx * 4 + (j4 & 3);
                float* dst = out + (((size_t)(b * S_ + ny * NH_ + nx) << 16) + gq * 4);
                st4(dst, (float)a.x, (float)a.y, (float)a.z, (float)a.w);
            }
        }
    }
    if ((blk | t) == 0) out[(size_t)B_ * S_ * N_] = 256.0f;  // output 1: S
}

extern "C" void kernel_launch(void* const* d_in, const int* in_sizes, int n_in,
                              void* d_out, int out_size, void* d_ws, size_t ws_size,
                              hipStream_t stream) {
    const float* x = (const float*)d_in[0];
    float* ws = (float*)d_ws;
    // ws layout (floats): cent0[32768] | part[1024*304]
    float* cent0 = ws;
    float* part  = ws + 32768;
    float* out   = (float*)d_out;

    static int coop_ok = -1;
    if (coop_ok < 0) {
        int nb = 0;
        hipError_t e = hipOccupancyMaxActiveBlocksPerMultiprocessor(&nb, k_fused, 256, 0);
        coop_ok = (e == hipSuccess && nb >= 4) ? 1 : 0;
    }

    if (coop_ok == 1) {
        void* args[] = {(void*)&x, (void*)&cent0, (void*)&part, (void*)&out};
        hipError_t e = hipLaunchCooperativeKernel((void*)k_fused, dim3(B_ * S_),
                                                  dim3(256), args, 0, stream);
        if (e == hipSuccess) return;
        coop_ok = 0;  // launch rejected — permanently fall back
    }

    hipLaunchKernelGGL(k_zero,  dim3(2048),    dim3(256), 0, stream, out);
    hipLaunchKernelGGL(k_cent0, dim3(B_ * S_), dim3(256), 0, stream, x, cent0);
    hipLaunchKernelGGL(k_part,  dim3(B_ * S_), dim3(256), 0, stream, x, cent0, part);
    hipLaunchKernelGGL(k_aff9,  dim3(B_ * S_), dim3(256), 0, stream, x, part, out);
}

// Round 7
// 346.152 us; speedup vs baseline: 1.0077x; 1.0073x over previous
//
#include <hip/hip_runtime.h>
#include <hip/hip_fp16.h>
#include <hip/hip_cooperative_groups.h>

namespace cg = cooperative_groups;

// SSN soft-superpixel assignment. Fixed shapes: x (4,32,256,256) fp32, s=16.
// M = 0 -> grid channels are identically zero; drop them (C=32).
//
// ROUND 7 MODEL (fit to R0..R6): harness in/out buffers sustain only
// ~0.9-1 TB/s from compute kernels; d_ws is fast (its poison fill runs at
// 6.1 TB/s); the best observed out-writer is the pure-stream k_zero shape
// (>=1.5 TB/s, R5 bound). So: (1) fused coop kernel reads x ONCE, computes
// both iterations, writes the 9.4 MB of neighborhood values to ws -- never
// touches out; (2) k_write, a no-LDS 32-waves/CU streaming kernel in the
// exact k_zero shape, writes ALL of out exactly once: zeros outside each
// plane's 3x3 tile neighborhood, values (read from L2-hot ws) inside.
#define B_  4
#define C_  32
#define W_  256
#define N_  65536   // H*W
#define NH_ 16      // 16x16 superpixel grid
#define S_  256
#define PADP 260    // xsh row stride (floats): 1040 B = 16B-mult, 4-way b128 conflict only
#define PADH 260    // affs row stride (halves): 520 B, 8B-mult for half4 reads
#define PSTR 304    // per-block partial stride: 288 num + 9 den + pad

typedef float vf4 __attribute__((ext_vector_type(4)));
typedef _Float16 h4 __attribute__((ext_vector_type(4)));

__device__ __forceinline__ float wave_sum(float v) {
    v += __shfl_down(v, 32);
    v += __shfl_down(v, 16);
    v += __shfl_down(v, 8);
    v += __shfl_down(v, 4);
    v += __shfl_down(v, 2);
    v += __shfl_down(v, 1);
    return v;  // lane 0 holds the 64-lane sum
}

// Stage this block's 16x16x32 tile of x into xsh[c][p] (p = py*16+px),
// coalesced float4: idx -> channel c = idx>>6, f4 p4 = idx&63.
__device__ __forceinline__ void stage_tile(const float* __restrict__ x,
                                           int b, int sy, int sx, int t,
                                           float (*xsh)[PADP]) {
    const float* base = x + (size_t)b * C_ * N_ + (sy * 16) * W_ + sx * 16;
    #pragma unroll
    for (int i = 0; i < 8; ++i) {
        const int idx = i * 256 + t;
        const int c = idx >> 6, p4 = idx & 63;
        const float4 v = *(const float4*)(base + (size_t)c * N_ + (p4 >> 2) * W_ + (p4 & 3) * 4);
        *(float4*)&xsh[c][p4 * 4] = v;
    }
}

// Per-pixel softmax over the 3x3 superpixel neighborhood (cl[k] zeroed for
// invalid k; masked to aff=0 anyway). Equivalent to ref softmax(-dist)+mask.
__device__ __forceinline__ void compute_aff(const float xv[C_], const float (*cl)[C_],
                                            int sy, int sx, float aff[9]) {
    float dist[9];
    #pragma unroll
    for (int k = 0; k < 9; ++k) {
        const int ny = sy + k / 3 - 1, nx = sx + k % 3 - 1;
        const bool valid = (ny >= 0) & (ny < NH_) & (nx >= 0) & (nx < NH_);
        float d = 0.f;
        #pragma unroll
        for (int c4 = 0; c4 < C_ / 4; ++c4) {
            const float4 cv = *(const float4*)&cl[k][c4 * 4];   // LDS broadcast
            const float d0 = xv[c4 * 4 + 0] - cv.x;
            const float d1 = xv[c4 * 4 + 1] - cv.y;
            const float d2 = xv[c4 * 4 + 2] - cv.z;
            const float d3 = xv[c4 * 4 + 3] - cv.w;
            d += d0 * d0 + d1 * d1 + d2 * d2 + d3 * d3;
        }
        dist[k] = valid ? d : 1e30f;
    }
    float mind = dist[0];
    #pragma unroll
    for (int k = 1; k < 9; ++k) mind = fminf(mind, dist[k]);
    float sum = 0.f;
    #pragma unroll
    for (int k = 0; k < 9; ++k) {
        const float e = (dist[k] < 1e29f) ? __expf(mind - dist[k]) : 0.f;
        aff[k] = e;
        sum += e;
    }
    const float inv = 1.f / sum;   // home superpixel always valid
    #pragma unroll
    for (int k = 0; k < 9; ++k) aff[k] *= inv;
}

// cent1[b,(ny,nx),c] = num/(den+1e-16), gathered from 9 source blocks'
// partials (part is ws-fast / L2-hot, 1.2 MB).
__device__ __forceinline__ float gather_cent1(const float* __restrict__ part,
                                              int b, int ny, int nx, int c) {
    float num = 0.f, den = 0.f;
    #pragma unroll
    for (int k2 = 0; k2 < 9; ++k2) {
        const int syp = ny - (k2 / 3 - 1), sxp = nx - (k2 % 3 - 1);
        if ((syp >= 0) & (syp < NH_) & (sxp >= 0) & (sxp < NH_)) {
            const size_t base = (size_t)(b * S_ + syp * NH_ + sxp) * PSTR;
            num += part[base + k2 * 32 + c];
            den += part[base + 288 + k2];
        }
    }
    return num / (den + 1e-16f);
}

// ---------------------------------------------------------------------------
// k_write: the ONLY toucher of `out`. Pure streaming store kernel, exact
// k_zero shape (2048 blocks x 256 thr = 8 blk/CU, 32 waves/CU, no LDS,
// 32 float4 per thread, 8 MB grid sweep stride). For each float4 of out:
// inside the plane's 3x3 tile neighborhood -> value from vals (L2-hot),
// else zero. vals[b][s_src][k][256] fp32, 9.4 MB in ws.
// ---------------------------------------------------------------------------
__global__ __launch_bounds__(256) void k_write(const float* __restrict__ vals,
                                               float* __restrict__ out) {
    const size_t tid = (size_t)blockIdx.x * 256 + threadIdx.x;   // 0 .. 524287
    vf4* po = (vf4*)out;
    #pragma unroll 4
    for (int i = 0; i < 32; ++i) {
        const size_t q = tid + (size_t)i * 524288;   // f4 index into out
        const int b   = (int)(q >> 22);              // plane batch (2^22 f4/batch)
        const int r   = (int)(q & 4194303);
        const int sp  = r >> 14;                     // plane s' (16384 f4/plane)
        const int n4  = r & 16383;
        const int py  = n4 >> 6, px4 = n4 & 63;      // pixel row, f4-col
        const int syp = sp >> 4,  sxp = sp & 15;
        const int ty  = py >> 4,  tx  = px4 >> 2;    // tile of this pixel
        vf4 v = {0.f, 0.f, 0.f, 0.f};
        if (((unsigned)(ty - syp + 1) <= 2u) & ((unsigned)(tx - sxp + 1) <= 2u)) {
            const int ssrc = ty * 16 + tx;
            const int kp   = (syp - ty + 1) * 3 + (sxp - tx + 1);
            const int pl   = (py & 15) * 16 + (px4 & 3) * 4;
            v = *(const vf4*)&vals[(((size_t)(b * S_ + ssrc) * 9) + kp) * 256 + pl];
        }
        po[q] = v;
    }
    if (tid == 0) out[(size_t)B_ * S_ * N_] = 256.0f;   // output 1: S
}

// ---------------------------------------------------------------------------
// Fused cooperative compute kernel: reads x once, writes cent0/part/vals
// to ws only. Never touches `out`.
// ---------------------------------------------------------------------------
__global__ __launch_bounds__(256, 4) void k_compute(const float* __restrict__ x,
                                                    float* __restrict__ cent0,
                                                    float* __restrict__ part,
                                                    float* __restrict__ vals) {
    const int blk = blockIdx.x;            // b*S_ + s
    const int b = blk >> 8, s = blk & 255;
    const int sy = s >> 4, sx = s & 15;
    const int t = threadIdx.x;
    const int w = t >> 6, lane = t & 63;
    __shared__ float cl[9][C_];
    __shared__ float xsh[C_][PADP];
    __shared__ _Float16 affs[9][PADH];
    __shared__ float lden[4][9];

    // ---- Phase 0: stage x once; cent0 = tile mean from LDS ----
    stage_tile(x, b, sy, sx, t, xsh);
    __syncthreads();
    #pragma unroll
    for (int i = 0; i < 8; ++i) {
        const int c = i * 4 + w;           // wave w covers channels {w,4+w,...}
        const float4 v = *(const float4*)&xsh[c][lane * 4];  // contiguous 1 KB/wave
        const float sm = wave_sum(v.x + v.y + v.z + v.w);
        if (lane == 0) cent0[(size_t)blk * C_ + c] = sm * (1.0f / 256.0f);
    }
    cg::this_grid().sync();

    // ---- Phase 1: iteration-0 affinities + num/den partials ----
    {   // cl fill: k=0..7 by all, k=8 by t<32
        const int k = t >> 5, c = t & 31;
        const int ny = sy + k / 3 - 1, nx = sx + k % 3 - 1;
        const bool valid = (ny >= 0) & (ny < NH_) & (nx >= 0) & (nx < NH_);
        cl[k][c] = valid ? cent0[(size_t)(b * S_ + ny * NH_ + nx) * C_ + c] : 0.f;
    }
    if (t < 32) {
        const int ny = sy + 1, nx = sx + 1;
        const bool valid = (ny < NH_) & (nx < NH_);
        cl[8][t] = valid ? cent0[(size_t)(b * S_ + ny * NH_ + nx) * C_ + t] : 0.f;
    }
    __syncthreads();
    float xv[C_];
    #pragma unroll
    for (int c = 0; c < C_; ++c) xv[c] = xsh[c][t];   // conflict-free
    float aff[9];
    compute_aff(xv, cl, sy, sx, aff);
    #pragma unroll
    for (int k = 0; k < 9; ++k) {
        affs[k][t] = (_Float16)aff[k];
        const float v = wave_sum(aff[k]);
        if (lane == 0) lden[w][k] = v;
    }
    __syncthreads();
    {   // Phase B: outputs t = k*32+c for k=0..7; t<32 also k=8.
        const int k = t >> 5, c = t & 31;
        float acc = 0.f;
        #pragma unroll 4
        for (int p = 0; p < 256; p += 4) {
            const h4 a = *(const h4*)&affs[k][p];
            const float4 xc = *(const float4*)&xsh[c][p];
            acc += (float)a.x * xc.x + (float)a.y * xc.y +
                   (float)a.z * xc.z + (float)a.w * xc.w;
        }
        part[(size_t)blk * PSTR + t] = acc;
    }
    if (t < 32) {
        float acc = 0.f;
        #pragma unroll 4
        for (int p = 0; p < 256; p += 4) {
            const h4 a = *(const h4*)&affs[8][p];
            const float4 xc = *(const float4*)&xsh[t][p];
            acc += (float)a.x * xc.x + (float)a.y * xc.y +
                   (float)a.z * xc.z + (float)a.w * xc.w;
        }
        part[(size_t)blk * PSTR + 256 + t] = acc;
    }
    if (t < 9)
        part[(size_t)blk * PSTR + 288 + t] =
            lden[0][t] + lden[1][t] + lden[2][t] + lden[3][t];
    cg::this_grid().sync();

    // ---- Phase 2: iteration-1 affinities vs gathered cent1 -> vals (ws) ----
    {   // cl = cent1 of the 9 neighbors, computed on the fly
        const int k = t >> 5, c = t & 31;
        const int ny = sy + k / 3 - 1, nx = sx + k % 3 - 1;
        const bool valid = (ny >= 0) & (ny < NH_) & (nx >= 0) & (nx < NH_);
        cl[k][c] = valid ? gather_cent1(part, b, ny, nx, c) : 0.f;
    }
    if (t < 32) {
        const int ny = sy + 1, nx = sx + 1;
        const bool valid = (ny < NH_) & (nx < NH_);
        cl[8][t] = valid ? gather_cent1(part, b, ny, nx, t) : 0.f;
    }
    __syncthreads();
    #pragma unroll
    for (int c = 0; c < C_; ++c) xv[c] = xsh[c][t];
    compute_aff(xv, cl, sy, sx, aff);
    // Direct per-thread write: vals[b][s][k][t] = aff[k] — 1 KB/k coalesced.
    #pragma unroll
    for (int k = 0; k < 9; ++k)
        vals[(((size_t)blk * 9) + k) * 256 + t] = aff[k];
}

// ---------------------------------------------------------------------------
// Non-coop fallback versions (same math, x read per-kernel)
// ---------------------------------------------------------------------------
__global__ __launch_bounds__(256) void k_cent0(const float* __restrict__ x,
                                               float* __restrict__ cent0) {
    const int blk = blockIdx.x;
    const int b = blk >> 8, s = blk & 255;
    const int sy = s >> 4, sx = s & 15;
    const int t = threadIdx.x;
    const int w = t >> 6, lane = t & 63;
    const float* base = x + (size_t)b * C_ * N_ + (sy * 16) * W_ + sx * 16;
    #pragma unroll
    for (int i = 0; i < 8; ++i) {
        const int c = i * 4 + w;
        const float4 v = *(const float4*)(base + (size_t)c * N_ + (lane >> 2) * W_ + (lane & 3) * 4);
        const float sm = wave_sum(v.x + v.y + v.z + v.w);
        if (lane == 0) cent0[(size_t)blk * C_ + c] = sm * (1.0f / 256.0f);
    }
}

__global__ __launch_bounds__(256, 4) void k_part(const float* __restrict__ x,
                                                 const float* __restrict__ cent0,
                                                 float* __restrict__ part) {
    const int blk = blockIdx.x;
    const int b = blk >> 8, s = blk & 255;
    const int sy = s >> 4, sx = s & 15;
    const int t = threadIdx.x;
    const int w = t >> 6, lane = t & 63;
    __shared__ float cl[9][C_];
    __shared__ float xsh[C_][PADP];
    __shared__ _Float16 affs[9][PADH];
    __shared__ float lden[4][9];
    {
        const int k = t >> 5, c = t & 31;
        const int ny = sy + k / 3 - 1, nx = sx + k % 3 - 1;
        const bool valid = (ny >= 0) & (ny < NH_) & (nx >= 0) & (nx < NH_);
        cl[k][c] = valid ? cent0[(size_t)(b * S_ + ny * NH_ + nx) * C_ + c] : 0.f;
    }
    if (t < 32) {
        const int ny = sy + 1, nx = sx + 1;
        const bool valid = (ny < NH_) & (nx < NH_);
        cl[8][t] = valid ? cent0[(size_t)(b * S_ + ny * NH_ + nx) * C_ + t] : 0.f;
    }
    stage_tile(x, b, sy, sx, t, xsh);
    __syncthreads();
    float xv[C_];
    #pragma unroll
    for (int c = 0; c < C_; ++c) xv[c] = xsh[c][t];
    float aff[9];
    compute_aff(xv, cl, sy, sx, aff);
    #pragma unroll
    for (int k = 0; k < 9; ++k) {
        affs[k][t] = (_Float16)aff[k];
        const float v = wave_sum(aff[k]);
        if (lane == 0) lden[w][k] = v;
    }
    __syncthreads();
    {
        const int k = t >> 5, c = t & 31;
        float acc = 0.f;
        #pragma unroll 4
        for (int p = 0; p < 256; p += 4) {
            const h4 a = *(const h4*)&affs[k][p];
            const float4 xc = *(const float4*)&xsh[c][p];
            acc += (float)a.x * xc.x + (float)a.y * xc.y +
                   (float)a.z * xc.z + (float)a.w * xc.w;
        }
        part[(size_t)blk * PSTR + t] = acc;
    }
    if (t < 32) {
        float acc = 0.f;
        #pragma unroll 4
        for (int p = 0; p < 256; p += 4) {
            const h4 a = *(const h4*)&affs[8][p];
            const float4 xc = *(const float4*)&xsh[t][p];
            acc += (float)a.x * xc.x + (float)a.y * xc.y +
                   (float)a.z * xc.z + (float)a.w * xc.w;
        }
        part[(size_t)blk * PSTR + 256 + t] = acc;
    }
    if (t < 9)
        part[(size_t)blk * PSTR + 288 + t] =
            lden[0][t] + lden[1][t] + lden[2][t] + lden[3][t];
}

__global__ __launch_bounds__(256, 4) void k_aff9v(const float* __restrict__ x,
                                                  const float* __restrict__ part,
                                                  float* __restrict__ vals) {
    const int blk = blockIdx.x;
    const int b = blk >> 8, s = blk & 255;
    const int sy = s >> 4, sx = s & 15;
    const int t = threadIdx.x;
    __shared__ float cl[9][C_];
    __shared__ float xsh[C_][PADP];
    {
        const int k = t >> 5, c = t & 31;
        const int ny = sy + k / 3 - 1, nx = sx + k % 3 - 1;
        const bool valid = (ny >= 0) & (ny < NH_) & (nx >= 0) & (nx < NH_);
        cl[k][c] = valid ? gather_cent1(part, b, ny, nx, c) : 0.f;
    }
    if (t < 32) {
        const int ny = sy + 1, nx = sx + 1;
        const bool valid = (ny < NH_) & (nx < NH_);
        cl[8][t] = valid ? gather_cent1(part, b, ny, nx, t) : 0.f;
    }
    stage_tile(x, b, sy, sx, t, xsh);
    __syncthreads();
    float xv[C_];
    #pragma unroll
    for (int c = 0; c < C_; ++c) xv[c] = xsh[c][t];
    float aff[9];
    compute_aff(xv, cl, sy, sx, aff);
    #pragma unroll
    for (int k = 0; k < 9; ++k)
        vals[(((size_t)blk * 9) + k) * 256 + t] = aff[k];
}

extern "C" void kernel_launch(void* const* d_in, const int* in_sizes, int n_in,
                              void* d_out, int out_size, void* d_ws, size_t ws_size,
                              hipStream_t stream) {
    const float* x = (const float*)d_in[0];
    float* ws = (float*)d_ws;
    // ws layout (floats): cent0[32768] | part[1024*304=311296] | vals[4*256*9*256=2359296]
    float* cent0 = ws;
    float* part  = ws + 32768;
    float* vals  = ws + 32768 + 311296;
    float* out   = (float*)d_out;

    static int coop_ok = -1;
    if (coop_ok < 0) {
        int nb = 0;
        hipError_t e = hipOccupancyMaxActiveBlocksPerMultiprocessor(&nb, k_compute, 256, 0);
        coop_ok = (e == hipSuccess && nb >= 4) ? 1 : 0;
    }

    bool launched = false;
    if (coop_ok == 1) {
        void* args[] = {(void*)&x, (void*)&cent0, (void*)&part, (void*)&vals};
        hipError_t e = hipLaunchCooperativeKernel((void*)k_compute, dim3(B_ * S_),
                                                  dim3(256), args, 0, stream);
        if (e == hipSuccess) launched = true;
        else coop_ok = 0;
    }
    if (!launched) {
        hipLaunchKernelGGL(k_cent0, dim3(B_ * S_), dim3(256), 0, stream, x, cent0);
        hipLaunchKernelGGL(k_part,  dim3(B_ * S_), dim3(256), 0, stream, x, cent0, part);
        hipLaunchKernelGGL(k_aff9v, dim3(B_ * S_), dim3(256), 0, stream, x, part, vals);
    }

    // Single pure-stream writer of out (the only kernel that touches out).
    hipLaunchKernelGGL(k_write, dim3(2048), dim3(256), 0, stream, vals, out);
}

// Round 8
// 338.080 us; speedup vs baseline: 1.0318x; 1.0239x over previous
//
#include <hip/hip_runtime.h>
#include <hip/hip_fp16.h>

// SSN soft-superpixel assignment. Fixed shapes: x (4,32,256,256) fp32, s=16.
// M = 0 -> grid channels are identically zero; drop them (C=32).
//
// ROUND 8 MODEL (decisive R7 counters): the sink was never the out-write.
// k_compute (no out traffic) took 229 us moving 35 MB -> the TILED x read
// (64 B granules at 1 KB stride, cold after the poison flush) runs at
// ~170 GB/s (DRAM row-activate per 64 B). The out-writer k_write is 117 us
// (2.3 TB/s), best measured. Fix: k_stage reads x LINEARLY (1 KB/wave,
// streaming rate), transposes via LDS into tile-major xt in ws (32 KB
// contiguous per tile, 1 KB-contiguous store chunks), and computes cent0
// on the fly (phase 0 + all grid syncs eliminated -> no cooperative launch).
// k_part/k_aff9v then stage tiles as contiguous 32 KB reads from L3-hot xt.
#define B_  4
#define C_  32
#define W_  256
#define N_  65536   // H*W
#define NH_ 16      // 16x16 superpixel grid
#define S_  256
#define PADP 260     // xsh row stride (floats)
#define PSTR 304     // per-block partial stride: 288 num + 9 den + pad
#define XT_TILE 8192 // floats per tile in xt: 32 ch x 256 px, contiguous

typedef float vf4 __attribute__((ext_vector_type(4)));

__device__ __forceinline__ float wave_sum(float v) {
    v += __shfl_down(v, 32);
    v += __shfl_down(v, 16);
    v += __shfl_down(v, 8);
    v += __shfl_down(v, 4);
    v += __shfl_down(v, 2);
    v += __shfl_down(v, 1);
    return v;
}

// ---------------------------------------------------------------------------
// K_A: coalesced x read -> tile-major xt + cent0. Block = (b, c-pair, sy):
// reads 2 channels x 16 rows x 1 KB (fully coalesced), LDS-transposes,
// writes 32 chunks of 1 KB contiguous into xt, and reduces per-tile means.
// ---------------------------------------------------------------------------
__global__ __launch_bounds__(256) void k_stage(const float* __restrict__ x,
                                               float* __restrict__ xt,
                                               float* __restrict__ cent0) {
    const int blk = blockIdx.x;                 // 1024 blocks
    const int b = blk >> 8, c2 = (blk >> 4) & 15, sy = blk & 15;
    const int t = threadIdx.x;
    __shared__ float lds[2][16][260];
    // Linear read: 2 ch x 16 rows x 256 cols. Wave reads 1 KB contiguous.
    #pragma unroll
    for (int i = 0; i < 8; ++i) {
        const int idx = i * 256 + t;            // f4 index 0..2047
        const int c = idx >> 10, y = (idx >> 6) & 15, f = idx & 63;
        const float4 v = *(const float4*)(
            x + (((size_t)(b * 32 + c2 * 2 + c) * 256) + sy * 16 + y) * 256 + f * 4);
        *(float4*)&lds[c][y][f * 4] = v;
    }
    __syncthreads();
    const int w = t >> 6, lane = t & 63;
    // Write 32 chunks (sx, c), each 1 KB contiguous in xt. 8 chunks/wave.
    #pragma unroll
    for (int j = 0; j < 8; ++j) {
        const int chunk = w * 8 + j;            // 0..31
        const int sx = chunk >> 1, c = chunk & 1;
        const int py = lane >> 2, p4 = lane & 3;
        const float4 v = *(const float4*)&lds[c][py][sx * 16 + p4 * 4];
        const size_t tile = (size_t)(b * 256 + sy * 16 + sx);
        *(float4*)(xt + tile * XT_TILE + (c2 * 2 + c) * 256 + py * 16 + p4 * 4) = v;
    }
    // cent0: per-(sx,c) tile mean. 32 pairs x 8 threads, 32 px each.
    {
        const int pair = t >> 3, sub = t & 7;
        const int sx = pair >> 1, c = pair & 1;
        float s = 0.f;
        #pragma unroll
        for (int i = 0; i < 32; ++i) {
            const int px = sub * 32 + i;        // 0..255
            s += lds[c][px >> 4][sx * 16 + (px & 15)];
        }
        s += __shfl_down(s, 4);
        s += __shfl_down(s, 2);
        s += __shfl_down(s, 1);
        if (sub == 0)
            cent0[(size_t)(b * 256 + sy * 16 + sx) * 32 + c2 * 2 + c] = s * (1.f / 256.f);
    }
}

// Stage tile blk from xt: pure contiguous 32 KB (wave reads 1 KB segments).
__device__ __forceinline__ void stage_tile_xt(const float* __restrict__ xt,
                                              int blk, int t, float (*xsh)[PADP]) {
    const float* base = xt + (size_t)blk * XT_TILE;
    #pragma unroll
    for (int i = 0; i < 8; ++i) {
        const int idx = i * 256 + t;
        const int c = idx >> 6, p4 = idx & 63;
        const float4 v = *(const float4*)(base + (size_t)idx * 4);
        *(float4*)&xsh[c][p4 * 4] = v;
    }
}

// Per-pixel softmax over the 3x3 superpixel neighborhood.
__device__ __forceinline__ void compute_aff(const float xv[C_], const float (*cl)[C_],
                                            int sy, int sx, float aff[9]) {
    float dist[9];
    #pragma unroll
    for (int k = 0; k < 9; ++k) {
        const int ny = sy + k / 3 - 1, nx = sx + k % 3 - 1;
        const bool valid = (ny >= 0) & (ny < NH_) & (nx >= 0) & (nx < NH_);
        float d = 0.f;
        #pragma unroll
        for (int c4 = 0; c4 < C_ / 4; ++c4) {
            const float4 cv = *(const float4*)&cl[k][c4 * 4];   // LDS broadcast
            const float d0 = xv[c4 * 4 + 0] - cv.x;
            const float d1 = xv[c4 * 4 + 1] - cv.y;
            const float d2 = xv[c4 * 4 + 2] - cv.z;
            const float d3 = xv[c4 * 4 + 3] - cv.w;
            d += d0 * d0 + d1 * d1 + d2 * d2 + d3 * d3;
        }
        dist[k] = valid ? d : 1e30f;
    }
    float mind = dist[0];
    #pragma unroll
    for (int k = 1; k < 9; ++k) mind = fminf(mind, dist[k]);
    float sum = 0.f;
    #pragma unroll
    for (int k = 0; k < 9; ++k) {
        const float e = (dist[k] < 1e29f) ? __expf(mind - dist[k]) : 0.f;
        aff[k] = e;
        sum += e;
    }
    const float inv = 1.f / sum;
    #pragma unroll
    for (int k = 0; k < 9; ++k) aff[k] *= inv;
}

// cent1 gather from 9 source blocks' partials (part is L2/L3-hot, 1.2 MB).
__device__ __forceinline__ float gather_cent1(const float* __restrict__ part,
                                              int b, int ny, int nx, int c) {
    float num = 0.f, den = 0.f;
    #pragma unroll
    for (int k2 = 0; k2 < 9; ++k2) {
        const int syp = ny - (k2 / 3 - 1), sxp = nx - (k2 % 3 - 1);
        if ((syp >= 0) & (syp < NH_) & (sxp >= 0) & (sxp < NH_)) {
            const size_t base = (size_t)(b * S_ + syp * NH_ + sxp) * PSTR;
            num += part[base + k2 * 32 + c];
            den += part[base + 288 + k2];
        }
    }
    return num / (den + 1e-16f);
}

typedef _Float16 h4_t;
typedef _Float16 h4 __attribute__((ext_vector_type(4)));
#define PADH 260

// K_B: iteration-0 affinities + num/den partials (x from xt).
__global__ __launch_bounds__(256, 4) void k_part(const float* __restrict__ xt,
                                                 const float* __restrict__ cent0,
                                                 float* __restrict__ part) {
    const int blk = blockIdx.x;
    const int b = blk >> 8, s = blk & 255;
    const int sy = s >> 4, sx = s & 15;
    const int t = threadIdx.x;
    const int w = t >> 6, lane = t & 63;
    __shared__ float cl[9][C_];
    __shared__ float xsh[C_][PADP];
    __shared__ _Float16 affs[9][PADH];
    __shared__ float lden[4][9];
    {   // cl fill: k=0..7 by all, k=8 by t<32
        const int k = t >> 5, c = t & 31;
        const int ny = sy + k / 3 - 1, nx = sx + k % 3 - 1;
        const bool valid = (ny >= 0) & (ny < NH_) & (nx >= 0) & (nx < NH_);
        cl[k][c] = valid ? cent0[(size_t)(b * S_ + ny * NH_ + nx) * C_ + c] : 0.f;
    }
    if (t < 32) {
        const int ny = sy + 1, nx = sx + 1;
        const bool valid = (ny < NH_) & (nx < NH_);
        cl[8][t] = valid ? cent0[(size_t)(b * S_ + ny * NH_ + nx) * C_ + t] : 0.f;
    }
    stage_tile_xt(xt, blk, t, xsh);
    __syncthreads();
    float xv[C_];
    #pragma unroll
    for (int c = 0; c < C_; ++c) xv[c] = xsh[c][t];
    float aff[9];
    compute_aff(xv, cl, sy, sx, aff);
    #pragma unroll
    for (int k = 0; k < 9; ++k) {
        affs[k][t] = (_Float16)aff[k];
        const float v = wave_sum(aff[k]);
        if (lane == 0) lden[w][k] = v;
    }
    __syncthreads();
    {
        const int k = t >> 5, c = t & 31;
        float acc = 0.f;
        #pragma unroll 4
        for (int p = 0; p < 256; p += 4) {
            const h4 a = *(const h4*)&affs[k][p];
            const float4 xc = *(const float4*)&xsh[c][p];
            acc += (float)a.x * xc.x + (float)a.y * xc.y +
                   (float)a.z * xc.z + (float)a.w * xc.w;
        }
        part[(size_t)blk * PSTR + t] = acc;
    }
    if (t < 32) {
        float acc = 0.f;
        #pragma unroll 4
        for (int p = 0; p < 256; p += 4) {
            const h4 a = *(const h4*)&affs[8][p];
            const float4 xc = *(const float4*)&xsh[t][p];
            acc += (float)a.x * xc.x + (float)a.y * xc.y +
                   (float)a.z * xc.z + (float)a.w * xc.w;
        }
        part[(size_t)blk * PSTR + 256 + t] = acc;
    }
    if (t < 9)
        part[(size_t)blk * PSTR + 288 + t] =
            lden[0][t] + lden[1][t] + lden[2][t] + lden[3][t];
}

// K_C: iteration-1 affinities vs gathered cent1 -> vals (ws).
__global__ __launch_bounds__(256, 4) void k_aff9v(const float* __restrict__ xt,
                                                  const float* __restrict__ part,
                                                  float* __restrict__ vals) {
    const int blk = blockIdx.x;
    const int b = blk >> 8, s = blk & 255;
    const int sy = s >> 4, sx = s & 15;
    const int t = threadIdx.x;
    __shared__ float cl[9][C_];
    __shared__ float xsh[C_][PADP];
    {
        const int k = t >> 5, c = t & 31;
        const int ny = sy + k / 3 - 1, nx = sx + k % 3 - 1;
        const bool valid = (ny >= 0) & (ny < NH_) & (nx >= 0) & (nx < NH_);
        cl[k][c] = valid ? gather_cent1(part, b, ny, nx, c) : 0.f;
    }
    if (t < 32) {
        const int ny = sy + 1, nx = sx + 1;
        const bool valid = (ny < NH_) & (nx < NH_);
        cl[8][t] = valid ? gather_cent1(part, b, ny, nx, t) : 0.f;
    }
    stage_tile_xt(xt, blk, t, xsh);
    __syncthreads();
    float xv[C_];
    #pragma unroll
    for (int c = 0; c < C_; ++c) xv[c] = xsh[c][t];
    float aff[9];
    compute_aff(xv, cl, sy, sx, aff);
    #pragma unroll
    for (int k = 0; k < 9; ++k)
        vals[(((size_t)blk * 9) + k) * 256 + t] = aff[k];
}

// K_D: the ONLY toucher of `out`. Pure streaming store kernel (R7-verified,
// 2.3 TB/s): zeros outside each plane's 3x3 tile neighborhood, values from
// L2/L3-hot vals inside.
__global__ __launch_bounds__(256) void k_write(const float* __restrict__ vals,
                                               float* __restrict__ out) {
    const size_t tid = (size_t)blockIdx.x * 256 + threadIdx.x;   // 0 .. 524287
    vf4* po = (vf4*)out;
    #pragma unroll 4
    for (int i = 0; i < 32; ++i) {
        const size_t q = tid + (size_t)i * 524288;   // f4 index into out
        const int b   = (int)(q >> 22);
        const int r   = (int)(q & 4194303);
        const int sp  = r >> 14;
        const int n4  = r & 16383;
        const int py  = n4 >> 6, px4 = n4 & 63;
        const int syp = sp >> 4,  sxp = sp & 15;
        const int ty  = py >> 4,  tx  = px4 >> 2;
        vf4 v = {0.f, 0.f, 0.f, 0.f};
        if (((unsigned)(ty - syp + 1) <= 2u) & ((unsigned)(tx - sxp + 1) <= 2u)) {
            const int ssrc = ty * 16 + tx;
            const int kp   = (syp - ty + 1) * 3 + (sxp - tx + 1);
            const int pl   = (py & 15) * 16 + (px4 & 3) * 4;
            v = *(const vf4*)&vals[(((size_t)(b * S_ + ssrc) * 9) + kp) * 256 + pl];
        }
        po[q] = v;
    }
    if (tid == 0) out[(size_t)B_ * S_ * N_] = 256.0f;   // output 1: S
}

extern "C" void kernel_launch(void* const* d_in, const int* in_sizes, int n_in,
                              void* d_out, int out_size, void* d_ws, size_t ws_size,
                              hipStream_t stream) {
    const float* x = (const float*)d_in[0];
    float* ws = (float*)d_ws;
    // ws layout (floats): xt[8388608] | cent0[32768] | part[311296] | vals[2359296]
    float* xt    = ws;
    float* cent0 = ws + 8388608;
    float* part  = ws + 8388608 + 32768;
    float* vals  = ws + 8388608 + 32768 + 311296;
    float* out   = (float*)d_out;

    hipLaunchKernelGGL(k_stage, dim3(1024),    dim3(256), 0, stream, x, xt, cent0);
    hipLaunchKernelGGL(k_part,  dim3(B_ * S_), dim3(256), 0, stream, xt, cent0, part);
    hipLaunchKernelGGL(k_aff9v, dim3(B_ * S_), dim3(256), 0, stream, xt, part, vals);
    hipLaunchKernelGGL(k_write, dim3(2048),    dim3(256), 0, stream, vals, out);
}